// Round 1
// baseline (5620.032 us; speedup 1.0000x reference)
//
#include <hip/hip_runtime.h>

// 2-layer GCN: h1 = relu(Ahat·(x@W1) + b1); out = log_softmax(Ahat·h1 @ W2 + b2)
// where layer-2 uses the identity Ahat·(h@W2) == (Ahat·h)@W2 (norm is scalar per edge),
// so both edge scatters run in HID=16 space (64B per message).

__global__ void zero_int(int* __restrict__ p, int n) {
    int i = blockIdx.x * blockDim.x + threadIdx.x;
    if (i < n) p[i] = 0;
}

__global__ void count_deg(const int* __restrict__ dst, int E, int* __restrict__ deg) {
    int e = blockIdx.x * blockDim.x + threadIdx.x;
    if (e < E) atomicAdd(&deg[dst[e]], 1);
}

__global__ void dinv_k(const int* __restrict__ deg, int n, float* __restrict__ dinv) {
    int i = blockIdx.x * blockDim.x + threadIdx.x;
    if (i < n) dinv[i] = rsqrtf((float)deg[i] + 1.0f);  // +1 = self-loop
}

// t1[i][h] = sum_k x[i][k] * W1[k][h]
// agg1[i][h] = b1[h] + t1[i][h] * dinv[i]^2   (self-loop term + bias pre-added)
__global__ __launch_bounds__(256) void gemm1_k(
        const float* __restrict__ x, const float* __restrict__ W1,
        const float* __restrict__ b1, const float* __restrict__ dinv,
        float* __restrict__ t1, float* __restrict__ agg1, int n) {
    __shared__ float W1s[256 * 16];
    for (int i = threadIdx.x; i < 256 * 16; i += 256) W1s[i] = W1[i];
    __syncthreads();
    int node = blockIdx.x * 16 + (threadIdx.x >> 4);
    int hid  = threadIdx.x & 15;
    if (node >= n) return;
    const float4* x4 = (const float4*)(x + (size_t)node * 256);
    float acc = 0.f;
#pragma unroll 8
    for (int k4 = 0; k4 < 64; ++k4) {
        float4 xv = x4[k4];
        int kb = k4 * 64 + hid;  // (4*k4)*16 + hid
        acc += xv.x * W1s[kb] + xv.y * W1s[kb + 16]
             + xv.z * W1s[kb + 32] + xv.w * W1s[kb + 48];
    }
    float di = dinv[node];
    t1[node * 16 + hid]   = acc;
    agg1[node * 16 + hid] = b1[hid] + acc * di * di;
}

// per edge: agg[dst] += t[src] * (dinv[src]*dinv[dst]), 16 floats
__global__ void scatter16(const int* __restrict__ src, const int* __restrict__ dst,
                          const float* __restrict__ dinv, const float* __restrict__ t,
                          float* __restrict__ agg, int E) {
    int e = blockIdx.x * blockDim.x + threadIdx.x;
    if (e >= E) return;
    int s = src[e], d = dst[e];
    float w = dinv[s] * dinv[d];
    const float4* ts = (const float4*)(t + (size_t)s * 16);
    float4 v0 = ts[0], v1 = ts[1], v2 = ts[2], v3 = ts[3];
    float* a = agg + (size_t)d * 16;
    atomicAdd(a + 0,  v0.x * w); atomicAdd(a + 1,  v0.y * w);
    atomicAdd(a + 2,  v0.z * w); atomicAdd(a + 3,  v0.w * w);
    atomicAdd(a + 4,  v1.x * w); atomicAdd(a + 5,  v1.y * w);
    atomicAdd(a + 6,  v1.z * w); atomicAdd(a + 7,  v1.w * w);
    atomicAdd(a + 8,  v2.x * w); atomicAdd(a + 9,  v2.y * w);
    atomicAdd(a + 10, v2.z * w); atomicAdd(a + 11, v2.w * w);
    atomicAdd(a + 12, v3.x * w); atomicAdd(a + 13, v3.y * w);
    atomicAdd(a + 14, v3.z * w); atomicAdd(a + 15, v3.w * w);
}

// h = relu(agg1) in place; agg2_init = h * dinv^2 (self-loop for layer 2)
__global__ void relu_init(float* __restrict__ agg1, float* __restrict__ agg2,
                          const float* __restrict__ dinv, int n16) {
    int i = blockIdx.x * blockDim.x + threadIdx.x;
    if (i >= n16) return;
    float h = agg1[i];
    h = h > 0.f ? h : 0.f;
    agg1[i] = h;
    float di = dinv[i >> 4];
    agg2[i] = h * di * di;
}

// logits[j] = b2[j] + sum_k agg2[i][k]*W2[k][j]; out = logits - logsumexp(logits)
__global__ __launch_bounds__(256) void final_k(
        const float* __restrict__ agg2, const float* __restrict__ W2,
        const float* __restrict__ b2, float* __restrict__ out, int n) {
    __shared__ float W2s[16 * 40];
    __shared__ float b2s[40];
    for (int i = threadIdx.x; i < 640; i += 256) W2s[i] = W2[i];
    if (threadIdx.x < 40) b2s[threadIdx.x] = b2[threadIdx.x];
    __syncthreads();
    int node = blockIdx.x * blockDim.x + threadIdx.x;
    if (node >= n) return;
    float g[16];
    const float4* a4 = (const float4*)(agg2 + (size_t)node * 16);
    float4 t0 = a4[0], t1 = a4[1], t2 = a4[2], t3 = a4[3];
    g[0]=t0.x; g[1]=t0.y; g[2]=t0.z; g[3]=t0.w;
    g[4]=t1.x; g[5]=t1.y; g[6]=t1.z; g[7]=t1.w;
    g[8]=t2.x; g[9]=t2.y; g[10]=t2.z; g[11]=t2.w;
    g[12]=t3.x; g[13]=t3.y; g[14]=t3.z; g[15]=t3.w;
    float lg[40];
    float mx = -1e30f;
#pragma unroll
    for (int j = 0; j < 40; ++j) {
        float acc = b2s[j];
#pragma unroll
        for (int k = 0; k < 16; ++k) acc += g[k] * W2s[k * 40 + j];
        lg[j] = acc;
        mx = fmaxf(mx, acc);
    }
    float sum = 0.f;
#pragma unroll
    for (int j = 0; j < 40; ++j) sum += __expf(lg[j] - mx);
    float lse = mx + logf(sum);
    float4* o4 = (float4*)(out + (size_t)node * 40);
#pragma unroll
    for (int j = 0; j < 10; ++j) {
        float4 v;
        v.x = lg[4 * j + 0] - lse;
        v.y = lg[4 * j + 1] - lse;
        v.z = lg[4 * j + 2] - lse;
        v.w = lg[4 * j + 3] - lse;
        o4[j] = v;
    }
}

extern "C" void kernel_launch(void* const* d_in, const int* in_sizes, int n_in,
                              void* d_out, int out_size, void* d_ws, size_t ws_size,
                              hipStream_t stream) {
    const float* x  = (const float*)d_in[0];
    const int*   ei = (const int*)d_in[1];
    const float* W1 = (const float*)d_in[2];
    const float* b1 = (const float*)d_in[3];
    const float* W2 = (const float*)d_in[4];
    const float* b2 = (const float*)d_in[5];

    int n = in_sizes[0] / 256;
    int E = in_sizes[1] / 2;
    const int* srcp = ei;       // edge_index[0]
    const int* dstp = ei + E;   // edge_index[1]

    float* ws   = (float*)d_ws;
    float* dinv = ws;                          // n floats
    int*   deg  = (int*)(ws + n);              // n ints
    float* bufA = ws + 2 * (size_t)n;          // 16n: t1, later agg2(16-dim)
    float* bufB = bufA + 16 * (size_t)n;       // 16n: agg1, later h
    float* out  = (float*)d_out;

    int gb_n  = (n + 255) / 256;
    int gb_e  = (E + 255) / 256;
    int gb_16 = (16 * n + 255) / 256;

    zero_int <<<gb_n, 256, 0, stream>>>(deg, n);
    count_deg<<<gb_e, 256, 0, stream>>>(dstp, E, deg);
    dinv_k   <<<gb_n, 256, 0, stream>>>(deg, n, dinv);
    gemm1_k  <<<(n + 15) / 16, 256, 0, stream>>>(x, W1, b1, dinv, bufA, bufB, n);
    scatter16<<<gb_e, 256, 0, stream>>>(srcp, dstp, dinv, bufA, bufB, E);  // layer 1
    relu_init<<<gb_16, 256, 0, stream>>>(bufB, bufA, dinv, 16 * n);        // h in bufB, agg2 init in bufA
    scatter16<<<gb_e, 256, 0, stream>>>(srcp, dstp, dinv, bufB, bufA, E);  // layer 2 (16-dim)
    final_k  <<<gb_n, 256, 0, stream>>>(bufA, W2, b2, out, n);
}

// Round 2
// 787.639 us; speedup vs baseline: 7.1353x; 7.1353x over previous
//
#include <hip/hip_runtime.h>

// 2-layer GCN. Layer-2 uses Ahat·(h@W2) == (Ahat·h)@W2, so both aggregations
// run in HID=16 space. Aggregation is gather-based over a CSR-by-dst built
// on-device each call (counting sort: count -> scan -> fill), replacing the
// 51.2M f32 atomics of the scatter formulation (R0->R1: WRITE_SIZE 1.6GB/dispatch).

__global__ void zero_int(int* __restrict__ p, int n) {
    int i = blockIdx.x * blockDim.x + threadIdx.x;
    if (i < n) p[i] = 0;
}

__global__ void count_deg(const int* __restrict__ dst, int E, int* __restrict__ deg) {
    int e = blockIdx.x * blockDim.x + threadIdx.x;
    if (e < E) atomicAdd(&deg[dst[e]], 1);
}

__global__ void dinv_k(const int* __restrict__ deg, int n, float* __restrict__ dinv) {
    int i = blockIdx.x * blockDim.x + threadIdx.x;
    if (i < n) dinv[i] = rsqrtf((float)deg[i] + 1.0f);  // +1 = self-loop
}

// ---- exclusive scan of deg[n] -> off[n] (+ off[n]=E), 256-wide blocks ----
__global__ __launch_bounds__(256) void scan_block(const int* __restrict__ deg, int n,
                                                  int* __restrict__ off, int* __restrict__ bsum) {
    __shared__ int s[256];
    int gid = blockIdx.x * 256 + threadIdx.x;
    int v = (gid < n) ? deg[gid] : 0;
    s[threadIdx.x] = v;
    __syncthreads();
    for (int d = 1; d < 256; d <<= 1) {
        int t = 0;
        if ((int)threadIdx.x >= d) t = s[threadIdx.x - d];
        __syncthreads();
        s[threadIdx.x] += t;
        __syncthreads();
    }
    if (gid < n) off[gid] = s[threadIdx.x] - v;  // exclusive
    if (threadIdx.x == 255) bsum[blockIdx.x] = s[255];
}

__global__ __launch_bounds__(512) void scan_sums(int* __restrict__ bsum, int nb) {
    __shared__ int s[512];
    int v = ((int)threadIdx.x < nb) ? bsum[threadIdx.x] : 0;
    s[threadIdx.x] = v;
    __syncthreads();
    for (int d = 1; d < 512; d <<= 1) {
        int t = 0;
        if ((int)threadIdx.x >= d) t = s[threadIdx.x - d];
        __syncthreads();
        s[threadIdx.x] += t;
        __syncthreads();
    }
    if ((int)threadIdx.x < nb) bsum[threadIdx.x] = s[threadIdx.x] - v;  // exclusive
}

__global__ __launch_bounds__(256) void add_base(int* __restrict__ off, const int* __restrict__ bsum,
                                                int n, int E) {
    int gid = blockIdx.x * 256 + threadIdx.x;
    if (gid < n) off[gid] += bsum[blockIdx.x];
    if (gid == 0) off[n] = E;
}

// place each edge into its dst bucket: src_s[pos], w_s[pos] = dinv[s]*dinv[d]
__global__ void fill_csr(const int* __restrict__ src, const int* __restrict__ dst,
                         const float* __restrict__ dinv, const int* __restrict__ off,
                         int* __restrict__ cursor, int* __restrict__ src_s,
                         float* __restrict__ w_s, int E) {
    int e = blockIdx.x * blockDim.x + threadIdx.x;
    if (e >= E) return;
    int s = src[e], d = dst[e];
    int pos = off[d] + atomicAdd(&cursor[d], 1);
    src_s[pos] = s;
    w_s[pos] = dinv[s] * dinv[d];
}

// t1[i][h] = sum_k x[i][k] * W1[k][h];  init1[i][h] = b1[h] + t1*dinv^2 (self-loop + bias)
__global__ __launch_bounds__(256) void gemm1_k(
        const float* __restrict__ x, const float* __restrict__ W1,
        const float* __restrict__ b1, const float* __restrict__ dinv,
        float* __restrict__ t1, float* __restrict__ init1, int n) {
    __shared__ float W1s[256 * 16];
    for (int i = threadIdx.x; i < 256 * 16; i += 256) W1s[i] = W1[i];
    __syncthreads();
    int node = blockIdx.x * 16 + (threadIdx.x >> 4);
    int hid  = threadIdx.x & 15;
    if (node >= n) return;
    const float4* x4 = (const float4*)(x + (size_t)node * 256);
    float acc = 0.f;
#pragma unroll 8
    for (int k4 = 0; k4 < 64; ++k4) {
        float4 xv = x4[k4];
        int kb = k4 * 64 + hid;
        acc += xv.x * W1s[kb] + xv.y * W1s[kb + 16]
             + xv.z * W1s[kb + 32] + xv.w * W1s[kb + 48];
    }
    float di = dinv[node];
    t1[node * 16 + hid]    = acc;
    init1[node * 16 + hid] = b1[hid] + acc * di * di;
}

// layer-1 aggregation: 16 lanes per node, gather t1[src]*w, + init1, relu -> h (in place in hbuf)
__global__ __launch_bounds__(256) void agg_l1(
        const int* __restrict__ off, const int* __restrict__ src_s, const float* __restrict__ w_s,
        const float* __restrict__ t1, float* __restrict__ hbuf, int n) {
    int node = blockIdx.x * 16 + (threadIdx.x >> 4);
    int h    = threadIdx.x & 15;
    if (node >= n) return;
    float acc = hbuf[(size_t)node * 16 + h];
    int e1 = off[node + 1];
    for (int e = off[node]; e < e1; ++e) {
        int s = src_s[e];
        float w = w_s[e];
        acc += t1[(size_t)s * 16 + h] * w;
    }
    hbuf[(size_t)node * 16 + h] = fmaxf(acc, 0.f);
}

// layer-2 aggregation: acc starts at self-loop h*dinv^2, gathers h[src]*w -> outb
__global__ __launch_bounds__(256) void agg_l2(
        const int* __restrict__ off, const int* __restrict__ src_s, const float* __restrict__ w_s,
        const float* __restrict__ hbuf, const float* __restrict__ dinv,
        float* __restrict__ outb, int n) {
    int node = blockIdx.x * 16 + (threadIdx.x >> 4);
    int h    = threadIdx.x & 15;
    if (node >= n) return;
    float di = dinv[node];
    float acc = hbuf[(size_t)node * 16 + h] * di * di;
    int e1 = off[node + 1];
    for (int e = off[node]; e < e1; ++e) {
        int s = src_s[e];
        float w = w_s[e];
        acc += hbuf[(size_t)s * 16 + h] * w;
    }
    outb[(size_t)node * 16 + h] = acc;
}

// logits[j] = b2[j] + sum_k agg2[i][k]*W2[k][j]; out = logits - logsumexp(logits)
__global__ __launch_bounds__(256) void final_k(
        const float* __restrict__ agg2, const float* __restrict__ W2,
        const float* __restrict__ b2, float* __restrict__ out, int n) {
    __shared__ float W2s[16 * 40];
    __shared__ float b2s[40];
    for (int i = threadIdx.x; i < 640; i += 256) W2s[i] = W2[i];
    if (threadIdx.x < 40) b2s[threadIdx.x] = b2[threadIdx.x];
    __syncthreads();
    int node = blockIdx.x * blockDim.x + threadIdx.x;
    if (node >= n) return;
    float g[16];
    const float4* a4 = (const float4*)(agg2 + (size_t)node * 16);
    float4 t0 = a4[0], t1 = a4[1], t2 = a4[2], t3 = a4[3];
    g[0]=t0.x; g[1]=t0.y; g[2]=t0.z; g[3]=t0.w;
    g[4]=t1.x; g[5]=t1.y; g[6]=t1.z; g[7]=t1.w;
    g[8]=t2.x; g[9]=t2.y; g[10]=t2.z; g[11]=t2.w;
    g[12]=t3.x; g[13]=t3.y; g[14]=t3.z; g[15]=t3.w;
    float lg[40];
    float mx = -1e30f;
#pragma unroll
    for (int j = 0; j < 40; ++j) {
        float acc = b2s[j];
#pragma unroll
        for (int k = 0; k < 16; ++k) acc += g[k] * W2s[k * 40 + j];
        lg[j] = acc;
        mx = fmaxf(mx, acc);
    }
    float sum = 0.f;
#pragma unroll
    for (int j = 0; j < 40; ++j) sum += __expf(lg[j] - mx);
    float lse = mx + logf(sum);
    float4* o4 = (float4*)(out + (size_t)node * 40);
#pragma unroll
    for (int j = 0; j < 10; ++j) {
        float4 v;
        v.x = lg[4 * j + 0] - lse;
        v.y = lg[4 * j + 1] - lse;
        v.z = lg[4 * j + 2] - lse;
        v.w = lg[4 * j + 3] - lse;
        o4[j] = v;
    }
}

extern "C" void kernel_launch(void* const* d_in, const int* in_sizes, int n_in,
                              void* d_out, int out_size, void* d_ws, size_t ws_size,
                              hipStream_t stream) {
    const float* x  = (const float*)d_in[0];
    const int*   ei = (const int*)d_in[1];
    const float* W1 = (const float*)d_in[2];
    const float* b1 = (const float*)d_in[3];
    const float* W2 = (const float*)d_in[4];
    const float* b2 = (const float*)d_in[5];

    int n = in_sizes[0] / 256;
    int E = in_sizes[1] / 2;
    const int* srcp = ei;       // edge_index[0]
    const int* dstp = ei + E;   // edge_index[1]

    // workspace layout (4-byte words): 36n + 2E + ~1k  (~40 MB)
    int*   deg    = (int*)d_ws;                 // n   } zeroed together
    int*   cursor = deg + n;                    // n   }
    int*   off    = cursor + n;                 // n+1
    int*   bsum   = off + n + 1;                // up to 1024
    float* dinv   = (float*)(bsum + 1024);      // n
    float* bufA   = dinv + n;                   // 16n : t1, later layer-2 result
    float* bufB   = bufA + 16 * (size_t)n;      // 16n : init1, then h
    int*   src_s  = (int*)(bufB + 16 * (size_t)n);  // E
    float* w_s    = (float*)(src_s + E);            // E
    float* out    = (float*)d_out;

    int gb_n  = (n + 255) / 256;
    int gb_e  = (E + 255) / 256;
    int nb    = gb_n;  // scan blocks

    zero_int  <<<(2 * n + 255) / 256, 256, 0, stream>>>(deg, 2 * n);  // deg + cursor
    count_deg <<<gb_e, 256, 0, stream>>>(dstp, E, deg);
    dinv_k    <<<gb_n, 256, 0, stream>>>(deg, n, dinv);
    scan_block<<<nb, 256, 0, stream>>>(deg, n, off, bsum);
    scan_sums <<<1, 512, 0, stream>>>(bsum, nb);
    add_base  <<<nb, 256, 0, stream>>>(off, bsum, n, E);
    gemm1_k   <<<(n + 15) / 16, 256, 0, stream>>>(x, W1, b1, dinv, bufA, bufB, n);
    fill_csr  <<<gb_e, 256, 0, stream>>>(srcp, dstp, dinv, off, cursor, src_s, w_s, E);
    agg_l1    <<<(n + 15) / 16, 256, 0, stream>>>(off, src_s, w_s, bufA, bufB, n);
    agg_l2    <<<(n + 15) / 16, 256, 0, stream>>>(off, src_s, w_s, bufB, dinv, bufA, n);
    final_k   <<<gb_n, 256, 0, stream>>>(bufA, W2, b2, out, n);
}

// Round 3
// 746.799 us; speedup vs baseline: 7.5255x; 1.0547x over previous
//
#include <hip/hip_runtime.h>

// 2-layer GCN. Both aggregations run in HID=16 space (layer-2 via
// Ahat·(h@W2) == (Ahat·h)@W2). Edge weights dinv[s]*dinv[d] are factored:
// features are pre-scaled by their own dinv (t1d = t1*dinv, hd = h*dinv),
// so the CSR stores ONLY src indices (4 B/edge) and aggregation is
//   out[d] = dinv[d] * (selfd[d] + sum_{s in N(d)} featd[s]).

__global__ void zero_int(int* __restrict__ p, int n) {
    int i = blockIdx.x * blockDim.x + threadIdx.x;
    if (i < n) p[i] = 0;
}

__global__ void count_deg(const int* __restrict__ dst, int E, int* __restrict__ deg) {
    int e = blockIdx.x * blockDim.x + threadIdx.x;
    if (e < E) atomicAdd(&deg[dst[e]], 1);
}

// exclusive block scan of deg -> off; also dinv = rsqrt(deg+1)
__global__ __launch_bounds__(256) void scan_block(const int* __restrict__ deg, int n,
                                                  int* __restrict__ off, int* __restrict__ bsum,
                                                  float* __restrict__ dinv) {
    __shared__ int s[256];
    int gid = blockIdx.x * 256 + threadIdx.x;
    int v = (gid < n) ? deg[gid] : 0;
    if (gid < n) dinv[gid] = rsqrtf((float)v + 1.0f);  // +1 = self-loop
    s[threadIdx.x] = v;
    __syncthreads();
    for (int d = 1; d < 256; d <<= 1) {
        int t = 0;
        if ((int)threadIdx.x >= d) t = s[threadIdx.x - d];
        __syncthreads();
        s[threadIdx.x] += t;
        __syncthreads();
    }
    if (gid < n) off[gid] = s[threadIdx.x] - v;  // exclusive
    if (threadIdx.x == 255) bsum[blockIdx.x] = s[255];
}

__global__ __launch_bounds__(512) void scan_sums(int* __restrict__ bsum, int nb) {
    __shared__ int s[512];
    int v = ((int)threadIdx.x < nb) ? bsum[threadIdx.x] : 0;
    s[threadIdx.x] = v;
    __syncthreads();
    for (int d = 1; d < 512; d <<= 1) {
        int t = 0;
        if ((int)threadIdx.x >= d) t = s[threadIdx.x - d];
        __syncthreads();
        s[threadIdx.x] += t;
        __syncthreads();
    }
    if ((int)threadIdx.x < nb) bsum[threadIdx.x] = s[threadIdx.x] - v;  // exclusive
}

// off += block base; cursor seeded = off (fill_csr atomics run on cursor)
__global__ __launch_bounds__(256) void add_base(int* __restrict__ off, int* __restrict__ cursor,
                                                const int* __restrict__ bsum, int n, int E) {
    int gid = blockIdx.x * 256 + threadIdx.x;
    if (gid < n) {
        int v = off[gid] + bsum[blockIdx.x];
        off[gid] = v;
        cursor[gid] = v;
    }
    if (gid == 0) off[n] = E;
}

__global__ void fill_csr(const int* __restrict__ src, const int* __restrict__ dst,
                         int* __restrict__ cursor, int* __restrict__ src_s, int E) {
    int e = blockIdx.x * blockDim.x + threadIdx.x;
    if (e >= E) return;
    int s = src[e], d = dst[e];
    int pos = atomicAdd(&cursor[d], 1);
    src_s[pos] = s;
}

// t1d[i][h] = (sum_k x[i][k] * W1[k][h]) * dinv[i]
__global__ __launch_bounds__(256) void gemm1_k(
        const float* __restrict__ x, const float* __restrict__ W1,
        const float* __restrict__ dinv, float* __restrict__ t1d, int n) {
    __shared__ float W1s[256 * 16];
    for (int i = threadIdx.x; i < 256 * 16; i += 256) W1s[i] = W1[i];
    __syncthreads();
    int node = blockIdx.x * 16 + (threadIdx.x >> 4);
    int hid  = threadIdx.x & 15;
    if (node >= n) return;
    const float4* x4 = (const float4*)(x + (size_t)node * 256);
    float acc = 0.f;
#pragma unroll 8
    for (int k4 = 0; k4 < 64; ++k4) {
        float4 xv = x4[k4];
        int kb = k4 * 64 + hid;
        acc += xv.x * W1s[kb] + xv.y * W1s[kb + 16]
             + xv.z * W1s[kb + 32] + xv.w * W1s[kb + 48];
    }
    t1d[(size_t)node * 16 + hid] = acc * dinv[node];
}

// h = relu(b1 + dinv[d]*(t1d[d] + sum t1d[s]));  hd = h * dinv[d]
__global__ __launch_bounds__(256) void agg_l1(
        const int* __restrict__ off, const int* __restrict__ src_s,
        const float* __restrict__ t1d, const float* __restrict__ dinv,
        const float* __restrict__ b1, float* __restrict__ hd, int n) {
    int node = blockIdx.x * 16 + (threadIdx.x >> 4);
    int h    = threadIdx.x & 15;
    if (node >= n) return;
    float di  = dinv[node];
    float acc = t1d[(size_t)node * 16 + h];  // self-loop term (di factored out)
    int e  = off[node];
    int e1 = off[node + 1];
    for (; e + 4 <= e1; e += 4) {
        int s0 = src_s[e], s1 = src_s[e + 1], s2 = src_s[e + 2], s3 = src_s[e + 3];
        float v0 = t1d[(size_t)s0 * 16 + h];
        float v1 = t1d[(size_t)s1 * 16 + h];
        float v2 = t1d[(size_t)s2 * 16 + h];
        float v3 = t1d[(size_t)s3 * 16 + h];
        acc += (v0 + v1) + (v2 + v3);
    }
    for (; e < e1; ++e) acc += t1d[(size_t)src_s[e] * 16 + h];
    float hv = fmaxf(b1[h] + di * acc, 0.f);
    hd[(size_t)node * 16 + h] = hv * di;
}

// out16[d] = dinv[d] * (hd[d] + sum hd[s])
__global__ __launch_bounds__(256) void agg_l2(
        const int* __restrict__ off, const int* __restrict__ src_s,
        const float* __restrict__ hd, const float* __restrict__ dinv,
        float* __restrict__ out16, int n) {
    int node = blockIdx.x * 16 + (threadIdx.x >> 4);
    int h    = threadIdx.x & 15;
    if (node >= n) return;
    float di  = dinv[node];
    float acc = hd[(size_t)node * 16 + h];  // self-loop term
    int e  = off[node];
    int e1 = off[node + 1];
    for (; e + 4 <= e1; e += 4) {
        int s0 = src_s[e], s1 = src_s[e + 1], s2 = src_s[e + 2], s3 = src_s[e + 3];
        float v0 = hd[(size_t)s0 * 16 + h];
        float v1 = hd[(size_t)s1 * 16 + h];
        float v2 = hd[(size_t)s2 * 16 + h];
        float v3 = hd[(size_t)s3 * 16 + h];
        acc += (v0 + v1) + (v2 + v3);
    }
    for (; e < e1; ++e) acc += hd[(size_t)src_s[e] * 16 + h];
    out16[(size_t)node * 16 + h] = di * acc;
}

// logits = b2 + out16 @ W2; out = logits - logsumexp
__global__ __launch_bounds__(256) void final_k(
        const float* __restrict__ agg2, const float* __restrict__ W2,
        const float* __restrict__ b2, float* __restrict__ out, int n) {
    __shared__ float W2s[16 * 40];
    __shared__ float b2s[40];
    for (int i = threadIdx.x; i < 640; i += 256) W2s[i] = W2[i];
    if (threadIdx.x < 40) b2s[threadIdx.x] = b2[threadIdx.x];
    __syncthreads();
    int node = blockIdx.x * blockDim.x + threadIdx.x;
    if (node >= n) return;
    float g[16];
    const float4* a4 = (const float4*)(agg2 + (size_t)node * 16);
    float4 t0 = a4[0], t1 = a4[1], t2 = a4[2], t3 = a4[3];
    g[0]=t0.x; g[1]=t0.y; g[2]=t0.z; g[3]=t0.w;
    g[4]=t1.x; g[5]=t1.y; g[6]=t1.z; g[7]=t1.w;
    g[8]=t2.x; g[9]=t2.y; g[10]=t2.z; g[11]=t2.w;
    g[12]=t3.x; g[13]=t3.y; g[14]=t3.z; g[15]=t3.w;
    float lg[40];
    float mx = -1e30f;
#pragma unroll
    for (int j = 0; j < 40; ++j) {
        float acc = b2s[j];
#pragma unroll
        for (int k = 0; k < 16; ++k) acc += g[k] * W2s[k * 40 + j];
        lg[j] = acc;
        mx = fmaxf(mx, acc);
    }
    float sum = 0.f;
#pragma unroll
    for (int j = 0; j < 40; ++j) sum += __expf(lg[j] - mx);
    float lse = mx + logf(sum);
    float4* o4 = (float4*)(out + (size_t)node * 40);
#pragma unroll
    for (int j = 0; j < 10; ++j) {
        float4 v;
        v.x = lg[4 * j + 0] - lse;
        v.y = lg[4 * j + 1] - lse;
        v.z = lg[4 * j + 2] - lse;
        v.w = lg[4 * j + 3] - lse;
        o4[j] = v;
    }
}

extern "C" void kernel_launch(void* const* d_in, const int* in_sizes, int n_in,
                              void* d_out, int out_size, void* d_ws, size_t ws_size,
                              hipStream_t stream) {
    const float* x  = (const float*)d_in[0];
    const int*   ei = (const int*)d_in[1];
    const float* W1 = (const float*)d_in[2];
    const float* b1 = (const float*)d_in[3];
    const float* W2 = (const float*)d_in[4];
    const float* b2 = (const float*)d_in[5];

    int n = in_sizes[0] / 256;
    int E = in_sizes[1] / 2;
    const int* srcp = ei;       // edge_index[0]
    const int* dstp = ei + E;   // edge_index[1]

    // workspace layout (4-byte words): ~35n + E + 1k  (~27 MB)
    int*   deg    = (int*)d_ws;                      // n
    int*   cursor = deg + n;                         // n
    int*   off    = cursor + n;                      // n+1
    int*   bsum   = off + n + 1;                     // up to 1024
    float* dinv   = (float*)(bsum + 1024);           // n
    float* bufA   = dinv + n;                        // 16n : t1d, later out16
    float* bufB   = bufA + 16 * (size_t)n;           // 16n : hd
    int*   src_s  = (int*)(bufB + 16 * (size_t)n);   // E
    float* out    = (float*)d_out;

    int gb_n = (n + 255) / 256;
    int gb_e = (E + 255) / 256;
    int nb   = gb_n;

    zero_int  <<<gb_n, 256, 0, stream>>>(deg, n);
    count_deg <<<gb_e, 256, 0, stream>>>(dstp, E, deg);
    scan_block<<<nb, 256, 0, stream>>>(deg, n, off, bsum, dinv);
    scan_sums <<<1, 512, 0, stream>>>(bsum, nb);
    add_base  <<<nb, 256, 0, stream>>>(off, cursor, bsum, n, E);
    gemm1_k   <<<(n + 15) / 16, 256, 0, stream>>>(x, W1, dinv, bufA, n);
    fill_csr  <<<gb_e, 256, 0, stream>>>(srcp, dstp, cursor, src_s, E);
    agg_l1    <<<(n + 15) / 16, 256, 0, stream>>>(off, src_s, bufA, dinv, b1, bufB, n);
    agg_l2    <<<(n + 15) / 16, 256, 0, stream>>>(off, src_s, bufB, dinv, bufA, n);
    final_k   <<<gb_n, 256, 0, stream>>>(bufA, W2, b2, out, n);
}

// Round 4
// 637.468 us; speedup vs baseline: 8.8162x; 1.1715x over previous
//
#include <hip/hip_runtime.h>

// 2-layer GCN, HID=16 space for both aggregations (Ahat·(h@W2) == (Ahat·h)@W2),
// edge weight dinv[s]*dinv[d] factored into per-node feature pre-scaling.
// Neighbor lists live in a PADDED bucket array: cursor[d] seeded to d*PAD, one
// atomicAdd per edge both counts degree and assigns the slot (kills count_deg +
// scan chain; R2 evidence: random 4B RMW ops ~20k/us are the currency).
// Slots >= PAD go to a bounded overflow list; fixup kernels atomicAdd those
// contributions into the UNSCALED pre-activation sums S (bias/dinv/relu applied
// in later passes), so the scheme is correct for any degree distribution.

#define OVF_CAP 16384

__global__ void seed_k(int* __restrict__ cursor, int n, int PAD, int* __restrict__ ovf_cnt) {
    int i = blockIdx.x * blockDim.x + threadIdx.x;
    if (i < n) cursor[i] = i * PAD;
    if (i == 0) *ovf_cnt = 0;
}

// 4 edges per thread (int4 loads) for memory-level parallelism.
__global__ __launch_bounds__(256) void fill_pad(
        const int* __restrict__ src, const int* __restrict__ dst,
        int* __restrict__ cursor, int* __restrict__ padded,
        int* __restrict__ ovf, int* __restrict__ ovf_cnt, int E, int PAD) {
    int t = blockIdx.x * blockDim.x + threadIdx.x;
    int e0 = t * 4;
    if (e0 + 3 < E) {
        int4 s4 = ((const int4*)src)[t];
        int4 d4 = ((const int4*)dst)[t];
        int p0 = atomicAdd(&cursor[d4.x], 1);
        int p1 = atomicAdd(&cursor[d4.y], 1);
        int p2 = atomicAdd(&cursor[d4.z], 1);
        int p3 = atomicAdd(&cursor[d4.w], 1);
        if (p0 < d4.x * PAD + PAD) padded[p0] = s4.x;
        else { int k = atomicAdd(ovf_cnt, 1); if (k < OVF_CAP) ovf[k] = e0; }
        if (p1 < d4.y * PAD + PAD) padded[p1] = s4.y;
        else { int k = atomicAdd(ovf_cnt, 1); if (k < OVF_CAP) ovf[k] = e0 + 1; }
        if (p2 < d4.z * PAD + PAD) padded[p2] = s4.z;
        else { int k = atomicAdd(ovf_cnt, 1); if (k < OVF_CAP) ovf[k] = e0 + 2; }
        if (p3 < d4.w * PAD + PAD) padded[p3] = s4.w;
        else { int k = atomicAdd(ovf_cnt, 1); if (k < OVF_CAP) ovf[k] = e0 + 3; }
    } else {
        for (int e = e0; e < E; ++e) {
            int s = src[e], d = dst[e];
            int p = atomicAdd(&cursor[d], 1);
            if (p < d * PAD + PAD) padded[p] = s;
            else { int k = atomicAdd(ovf_cnt, 1); if (k < OVF_CAP) ovf[k] = e; }
        }
    }
}

// cnt = slots to gather (<=PAD); dinv from TRUE degree (incl. overflow) + self-loop
__global__ void cnt_k(const int* __restrict__ cursor, int n, int PAD,
                      int* __restrict__ cnt, float* __restrict__ dinv) {
    int i = blockIdx.x * blockDim.x + threadIdx.x;
    if (i >= n) return;
    int c = cursor[i] - i * PAD;
    cnt[i] = c < PAD ? c : PAD;
    dinv[i] = rsqrtf((float)c + 1.0f);
}

// t1d[i][h] = (sum_k x[i][k] * W1[k][h]) * dinv[i]
__global__ __launch_bounds__(256) void gemm1_k(
        const float* __restrict__ x, const float* __restrict__ W1,
        const float* __restrict__ dinv, float* __restrict__ t1d, int n) {
    __shared__ float W1s[256 * 16];
    for (int i = threadIdx.x; i < 256 * 16; i += 256) W1s[i] = W1[i];
    __syncthreads();
    int node = blockIdx.x * 16 + (threadIdx.x >> 4);
    int hid  = threadIdx.x & 15;
    if (node >= n) return;
    const float4* x4 = (const float4*)(x + (size_t)node * 256);
    float acc = 0.f;
#pragma unroll 8
    for (int k4 = 0; k4 < 64; ++k4) {
        float4 xv = x4[k4];
        int kb = k4 * 64 + hid;
        acc += xv.x * W1s[kb] + xv.y * W1s[kb + 16]
             + xv.z * W1s[kb + 32] + xv.w * W1s[kb + 48];
    }
    t1d[(size_t)node * 16 + hid] = acc * dinv[node];
}

// S[d] = feat[d] + sum_{slots} feat[padded[..]]   (UNSCALED, no bias/relu)
// 4 lanes per node, float4 per lane.
__global__ __launch_bounds__(256) void agg_k(
        const int* __restrict__ padded, const int* __restrict__ cnt,
        const float* __restrict__ feat, float* __restrict__ S, int n, int PAD) {
    int node = blockIdx.x * 64 + (threadIdx.x >> 2);
    int q    = threadIdx.x & 3;
    if (node >= n) return;
    const float4* f4 = (const float4*)feat;
    float4 acc = f4[(size_t)node * 4 + q];  // self-loop term
    int c = cnt[node];
    int base = node * PAD;
    int j = 0;
    for (; j + 4 <= c; j += 4) {
        int s0 = padded[base + j],     s1 = padded[base + j + 1];
        int s2 = padded[base + j + 2], s3 = padded[base + j + 3];
        float4 v0 = f4[(size_t)s0 * 4 + q];
        float4 v1 = f4[(size_t)s1 * 4 + q];
        float4 v2 = f4[(size_t)s2 * 4 + q];
        float4 v3 = f4[(size_t)s3 * 4 + q];
        acc.x += (v0.x + v1.x) + (v2.x + v3.x);
        acc.y += (v0.y + v1.y) + (v2.y + v3.y);
        acc.z += (v0.z + v1.z) + (v2.z + v3.z);
        acc.w += (v0.w + v1.w) + (v2.w + v3.w);
    }
    for (; j < c; ++j) {
        float4 v = f4[(size_t)padded[base + j] * 4 + q];
        acc.x += v.x; acc.y += v.y; acc.z += v.z; acc.w += v.w;
    }
    ((float4*)S)[(size_t)node * 4 + q] = acc;
}

// overflow edges: S[d] += feat[s]  (16 atomics each; normally zero edges)
__global__ void fix_k(const int* __restrict__ ovf, const int* __restrict__ ovf_cnt,
                      const int* __restrict__ src, const int* __restrict__ dst,
                      const float* __restrict__ feat, float* __restrict__ S) {
    int cnt = *ovf_cnt;
    if (cnt > OVF_CAP) cnt = OVF_CAP;
    for (int i = blockIdx.x * blockDim.x + threadIdx.x; i < cnt;
         i += gridDim.x * blockDim.x) {
        int e = ovf[i];
        int s = src[e], d = dst[e];
        for (int h = 0; h < 16; ++h)
            atomicAdd(&S[(size_t)d * 16 + h], feat[(size_t)s * 16 + h]);
    }
}

// hd[i] = relu(b1 + dinv[i]*S[i]) * dinv[i]   (in place, one node per thread)
__global__ void relu_k(float* __restrict__ S, const float* __restrict__ dinv,
                       const float* __restrict__ b1, int n) {
    int node = blockIdx.x * blockDim.x + threadIdx.x;
    if (node >= n) return;
    float di = dinv[node];
    float4* row = (float4*)S + (size_t)node * 4;
    const float4* b4 = (const float4*)b1;
#pragma unroll
    for (int q = 0; q < 4; ++q) {
        float4 v = row[q], b = b4[q];
        v.x = fmaxf(b.x + di * v.x, 0.f) * di;
        v.y = fmaxf(b.y + di * v.y, 0.f) * di;
        v.z = fmaxf(b.z + di * v.z, 0.f) * di;
        v.w = fmaxf(b.w + di * v.w, 0.f) * di;
        row[q] = v;
    }
}

// logits = b2 + (dinv*S2) @ W2; out = logits - logsumexp
__global__ __launch_bounds__(256) void final_k(
        const float* __restrict__ S2, const float* __restrict__ dinv,
        const float* __restrict__ W2, const float* __restrict__ b2,
        float* __restrict__ out, int n) {
    __shared__ float W2s[16 * 40];
    __shared__ float b2s[40];
    for (int i = threadIdx.x; i < 640; i += 256) W2s[i] = W2[i];
    if (threadIdx.x < 40) b2s[threadIdx.x] = b2[threadIdx.x];
    __syncthreads();
    int node = blockIdx.x * blockDim.x + threadIdx.x;
    if (node >= n) return;
    float di = dinv[node];
    float g[16];
    const float4* a4 = (const float4*)(S2 + (size_t)node * 16);
    float4 t0 = a4[0], t1 = a4[1], t2 = a4[2], t3 = a4[3];
    g[0]=di*t0.x; g[1]=di*t0.y; g[2]=di*t0.z; g[3]=di*t0.w;
    g[4]=di*t1.x; g[5]=di*t1.y; g[6]=di*t1.z; g[7]=di*t1.w;
    g[8]=di*t2.x; g[9]=di*t2.y; g[10]=di*t2.z; g[11]=di*t2.w;
    g[12]=di*t3.x; g[13]=di*t3.y; g[14]=di*t3.z; g[15]=di*t3.w;
    float lg[40];
    float mx = -1e30f;
#pragma unroll
    for (int j = 0; j < 40; ++j) {
        float acc = b2s[j];
#pragma unroll
        for (int k = 0; k < 16; ++k) acc += g[k] * W2s[k * 40 + j];
        lg[j] = acc;
        mx = fmaxf(mx, acc);
    }
    float sum = 0.f;
#pragma unroll
    for (int j = 0; j < 40; ++j) sum += __expf(lg[j] - mx);
    float lse = mx + logf(sum);
    float4* o4 = (float4*)(out + (size_t)node * 40);
#pragma unroll
    for (int j = 0; j < 10; ++j) {
        float4 v;
        v.x = lg[4 * j + 0] - lse;
        v.y = lg[4 * j + 1] - lse;
        v.z = lg[4 * j + 2] - lse;
        v.w = lg[4 * j + 3] - lse;
        o4[j] = v;
    }
}

extern "C" void kernel_launch(void* const* d_in, const int* in_sizes, int n_in,
                              void* d_out, int out_size, void* d_ws, size_t ws_size,
                              hipStream_t stream) {
    const float* x  = (const float*)d_in[0];
    const int*   ei = (const int*)d_in[1];
    const float* W1 = (const float*)d_in[2];
    const float* b1 = (const float*)d_in[3];
    const float* W2 = (const float*)d_in[4];
    const float* b2 = (const float*)d_in[5];

    int n = in_sizes[0] / 256;
    int E = in_sizes[1] / 2;
    const int* srcp = ei;       // edge_index[0]
    const int* dstp = ei + E;   // edge_index[1]

    // ws layout (words): cursor n | cnt n | dinv n | ovf_cnt 16 | ovf OVF_CAP
    //                    | bufA 16n | bufB 16n | padded PAD*n
    size_t fixed_words = 35 * (size_t)n + 16 + OVF_CAP;
    long long avail = (long long)(ws_size / 4) - (long long)fixed_words;
    int PAD = (int)(avail / n);
    if (PAD > 96) PAD = 96;
    if (PAD < 8)  PAD = 8;   // overflow path keeps this correct regardless

    int*   cursor  = (int*)d_ws;                     // n
    int*   cnt     = cursor + n;                     // n
    float* dinv    = (float*)(cnt + n);              // n
    int*   ovf_cnt = (int*)(dinv + n);               // 16
    int*   ovf     = ovf_cnt + 16;                   // OVF_CAP
    float* bufA    = (float*)(ovf + OVF_CAP);        // 16n : t1d, later S2
    float* bufB    = bufA + 16 * (size_t)n;          // 16n : S1, later hd
    int*   padded  = (int*)(bufB + 16 * (size_t)n);  // PAD*n
    float* out     = (float*)d_out;

    int gb_n = (n + 255) / 256;
    int gb_f = ((E + 3) / 4 + 255) / 256;

    seed_k  <<<gb_n, 256, 0, stream>>>(cursor, n, PAD, ovf_cnt);
    fill_pad<<<gb_f, 256, 0, stream>>>(srcp, dstp, cursor, padded, ovf, ovf_cnt, E, PAD);
    cnt_k   <<<gb_n, 256, 0, stream>>>(cursor, n, PAD, cnt, dinv);
    gemm1_k <<<(n + 15) / 16, 256, 0, stream>>>(x, W1, dinv, bufA, n);
    agg_k   <<<(n + 63) / 64, 256, 0, stream>>>(padded, cnt, bufA, bufB, n, PAD);  // layer 1
    fix_k   <<<64, 256, 0, stream>>>(ovf, ovf_cnt, srcp, dstp, bufA, bufB);
    relu_k  <<<gb_n, 256, 0, stream>>>(bufB, dinv, b1, n);                         // bufB = hd
    agg_k   <<<(n + 63) / 64, 256, 0, stream>>>(padded, cnt, bufB, bufA, n, PAD);  // layer 2
    fix_k   <<<64, 256, 0, stream>>>(ovf, ovf_cnt, srcp, dstp, bufB, bufA);
    final_k <<<gb_n, 256, 0, stream>>>(bufA, dinv, W2, b2, out, n);
}

// Round 5
// 613.038 us; speedup vs baseline: 9.1675x; 1.0399x over previous
//
#include <hip/hip_runtime.h>

// 2-layer GCN, HID=16 space for both aggregations (Ahat·(h@W2) == (Ahat·h)@W2),
// edge weight dinv[s]*dinv[d] factored into per-node feature pre-scaling.
// Adjacency = per-dst LINKED LISTS built with one atomicExch per edge:
//   prev = atomicExch(&head[d], e); chain[e] = {prev, src[e]}  (store coalesced).
// Evidence R0-R3: random 4B RMW ops run at ~20-30k/us device-wide regardless of
// ILP; fill_pad spent 2 random ops/edge (atomic + bucket store), this spends 1.
// Aggregation walks chains with 4 lanes/node; 16 independent chains per wave
// hide the dependent-hop latency.

__global__ __launch_bounds__(256) void link_k(
        const int* __restrict__ src, const int* __restrict__ dst,
        int* __restrict__ head, int2* __restrict__ chain, int E) {
    int t = blockIdx.x * blockDim.x + threadIdx.x;
    int e0 = t * 4;
    if (e0 + 3 < E) {
        int4 s4 = ((const int4*)src)[t];
        int4 d4 = ((const int4*)dst)[t];
        int p0 = atomicExch(&head[d4.x], e0);
        int p1 = atomicExch(&head[d4.y], e0 + 1);
        int p2 = atomicExch(&head[d4.z], e0 + 2);
        int p3 = atomicExch(&head[d4.w], e0 + 3);
        chain[e0]     = make_int2(p0, s4.x);
        chain[e0 + 1] = make_int2(p1, s4.y);
        chain[e0 + 2] = make_int2(p2, s4.z);
        chain[e0 + 3] = make_int2(p3, s4.w);
    } else {
        for (int e = e0; e < E; ++e) {
            int p = atomicExch(&head[dst[e]], e);
            chain[e] = make_int2(p, src[e]);
        }
    }
}

// walk chain once to get true degree -> dinv = rsqrt(deg+1)  (+1 self-loop)
__global__ void deg_k(const int* __restrict__ head, const int2* __restrict__ chain,
                      float* __restrict__ dinv, int n) {
    int i = blockIdx.x * blockDim.x + threadIdx.x;
    if (i >= n) return;
    int c = 0;
    int e = head[i];
    while (e >= 0) { ++c; e = chain[e].x; }
    dinv[i] = rsqrtf((float)c + 1.0f);
}

// t1d[i][h] = (sum_k x[i][k] * W1[k][h]) * dinv[i]
__global__ __launch_bounds__(256) void gemm1_k(
        const float* __restrict__ x, const float* __restrict__ W1,
        const float* __restrict__ dinv, float* __restrict__ t1d, int n) {
    __shared__ float W1s[256 * 16];
    for (int i = threadIdx.x; i < 256 * 16; i += 256) W1s[i] = W1[i];
    __syncthreads();
    int node = blockIdx.x * 16 + (threadIdx.x >> 4);
    int hid  = threadIdx.x & 15;
    if (node >= n) return;
    const float4* x4 = (const float4*)(x + (size_t)node * 256);
    float acc = 0.f;
#pragma unroll 8
    for (int k4 = 0; k4 < 64; ++k4) {
        float4 xv = x4[k4];
        int kb = k4 * 64 + hid;
        acc += xv.x * W1s[kb] + xv.y * W1s[kb + 16]
             + xv.z * W1s[kb + 32] + xv.w * W1s[kb + 48];
    }
    t1d[(size_t)node * 16 + hid] = acc * dinv[node];
}

// layer 1: hd[d] = relu(b1 + dinv[d]*(t1d[d] + sum_chain t1d[s])) * dinv[d]
__global__ __launch_bounds__(256) void agg1_k(
        const int* __restrict__ head, const int2* __restrict__ chain,
        const float* __restrict__ t1d, const float* __restrict__ dinv,
        const float* __restrict__ b1, float* __restrict__ hd, int n) {
    int node = blockIdx.x * 64 + (threadIdx.x >> 2);
    int q    = threadIdx.x & 3;
    if (node >= n) return;
    const float4* f4 = (const float4*)t1d;
    float4 acc = f4[(size_t)node * 4 + q];  // self-loop term
    int e = head[node];
    while (e >= 0) {
        int2 c = chain[e];
        float4 v = f4[(size_t)c.y * 4 + q];
        acc.x += v.x; acc.y += v.y; acc.z += v.z; acc.w += v.w;
        e = c.x;
    }
    float di = dinv[node];
    float4 b = ((const float4*)b1)[q];
    float4 r;
    r.x = fmaxf(b.x + di * acc.x, 0.f) * di;
    r.y = fmaxf(b.y + di * acc.y, 0.f) * di;
    r.z = fmaxf(b.z + di * acc.z, 0.f) * di;
    r.w = fmaxf(b.w + di * acc.w, 0.f) * di;
    ((float4*)hd)[(size_t)node * 4 + q] = r;
}

// layer 2: out16[d] = dinv[d] * (hd[d] + sum_chain hd[s])
__global__ __launch_bounds__(256) void agg2_k(
        const int* __restrict__ head, const int2* __restrict__ chain,
        const float* __restrict__ hd, const float* __restrict__ dinv,
        float* __restrict__ out16, int n) {
    int node = blockIdx.x * 64 + (threadIdx.x >> 2);
    int q    = threadIdx.x & 3;
    if (node >= n) return;
    const float4* f4 = (const float4*)hd;
    float4 acc = f4[(size_t)node * 4 + q];  // self-loop term
    int e = head[node];
    while (e >= 0) {
        int2 c = chain[e];
        float4 v = f4[(size_t)c.y * 4 + q];
        acc.x += v.x; acc.y += v.y; acc.z += v.z; acc.w += v.w;
        e = c.x;
    }
    float di = dinv[node];
    float4 r; r.x = di * acc.x; r.y = di * acc.y; r.z = di * acc.z; r.w = di * acc.w;
    ((float4*)out16)[(size_t)node * 4 + q] = r;
}

// logits = b2 + g16 @ W2; out = logits - logsumexp(logits)
__global__ __launch_bounds__(256) void final_k(
        const float* __restrict__ g16, const float* __restrict__ W2,
        const float* __restrict__ b2, float* __restrict__ out, int n) {
    __shared__ float W2s[16 * 40];
    __shared__ float b2s[40];
    for (int i = threadIdx.x; i < 640; i += 256) W2s[i] = W2[i];
    if (threadIdx.x < 40) b2s[threadIdx.x] = b2[threadIdx.x];
    __syncthreads();
    int node = blockIdx.x * blockDim.x + threadIdx.x;
    if (node >= n) return;
    float g[16];
    const float4* a4 = (const float4*)(g16 + (size_t)node * 16);
    float4 t0 = a4[0], t1 = a4[1], t2 = a4[2], t3 = a4[3];
    g[0]=t0.x; g[1]=t0.y; g[2]=t0.z; g[3]=t0.w;
    g[4]=t1.x; g[5]=t1.y; g[6]=t1.z; g[7]=t1.w;
    g[8]=t2.x; g[9]=t2.y; g[10]=t2.z; g[11]=t2.w;
    g[12]=t3.x; g[13]=t3.y; g[14]=t3.z; g[15]=t3.w;
    float lg[40];
    float mx = -1e30f;
#pragma unroll
    for (int j = 0; j < 40; ++j) {
        float acc = b2s[j];
#pragma unroll
        for (int k = 0; k < 16; ++k) acc += g[k] * W2s[k * 40 + j];
        lg[j] = acc;
        mx = fmaxf(mx, acc);
    }
    float sum = 0.f;
#pragma unroll
    for (int j = 0; j < 40; ++j) sum += __expf(lg[j] - mx);
    float lse = mx + logf(sum);
    float4* o4 = (float4*)(out + (size_t)node * 40);
#pragma unroll
    for (int j = 0; j < 10; ++j) {
        float4 v;
        v.x = lg[4 * j + 0] - lse;
        v.y = lg[4 * j + 1] - lse;
        v.z = lg[4 * j + 2] - lse;
        v.w = lg[4 * j + 3] - lse;
        o4[j] = v;
    }
}

extern "C" void kernel_launch(void* const* d_in, const int* in_sizes, int n_in,
                              void* d_out, int out_size, void* d_ws, size_t ws_size,
                              hipStream_t stream) {
    const float* x  = (const float*)d_in[0];
    const int*   ei = (const int*)d_in[1];
    const float* W1 = (const float*)d_in[2];
    const float* b1 = (const float*)d_in[3];
    const float* W2 = (const float*)d_in[4];
    const float* b2 = (const float*)d_in[5];

    int n = in_sizes[0] / 256;
    int E = in_sizes[1] / 2;
    const int* srcp = ei;       // edge_index[0]
    const int* dstp = ei + E;   // edge_index[1]

    // ws layout (4-byte words): head n | dinv n | bufA 16n | bufB 16n | chain 2E
    size_t off_words = 34 * (size_t)n;
    off_words = (off_words + 1) & ~(size_t)1;       // 8B-align chain
    int*   head  = (int*)d_ws;                      // n
    float* dinv  = (float*)head + n;                // n
    float* bufA  = dinv + n;                        // 16n : t1d, later out16
    float* bufB  = bufA + 16 * (size_t)n;           // 16n : hd
    int2*  chain = (int2*)((int*)d_ws + off_words); // E int2
    float* out   = (float*)d_out;

    int gb_n = (n + 255) / 256;
    int gb_l = ((E + 3) / 4 + 255) / 256;

    hipMemsetAsync(head, 0xFF, (size_t)n * 4, stream);  // head[i] = -1
    link_k <<<gb_l, 256, 0, stream>>>(srcp, dstp, head, chain, E);
    deg_k  <<<gb_n, 256, 0, stream>>>(head, chain, dinv, n);
    gemm1_k<<<(n + 15) / 16, 256, 0, stream>>>(x, W1, dinv, bufA, n);
    agg1_k <<<(n + 63) / 64, 256, 0, stream>>>(head, chain, bufA, dinv, b1, bufB, n);
    agg2_k <<<(n + 63) / 64, 256, 0, stream>>>(head, chain, bufB, dinv, bufA, n);
    final_k<<<gb_n, 256, 0, stream>>>(bufA, W2, b2, out, n);
}

// Round 6
// 422.817 us; speedup vs baseline: 13.2919x; 1.4499x over previous
//
#include <hip/hip_runtime.h>

// 2-layer GCN, HID=16 space for both aggregations (Ahat·(h@W2) == (Ahat·h)@W2),
// edge weight dinv[s]*dinv[d] factored into per-node feature pre-scaling.
// Adjacency built by TWO-LEVEL COUNTING SORT:
//   binA: LDS histogram per block over buckets (dst>>8), ONE global atomicAdd per
//         (block,bucket) (~153k RMW total vs 3.2M per-edge — R0-R4 evidence: random
//         global RMWs run at ~20-30k/us device-wide and dominated every variant),
//         then scatter packed (src<<8|dst_low) into padded bucket regions.
//   binB: per-bucket LDS counting sort by dst_low8 -> sorted CSR + degrees, no
//         global atomics, coalesced in-place writeback.
// Aggregation = flat CSR gather, 4 lanes/node, no atomics, no pointer chasing.
// Bucket cap = mean+11sigma; overflow edges go to a bounded list with always-run
// fixup kernels (atomicAdd into unscaled sums), correct for any distribution.

#define BSH 8                 // bucket = dst >> 8  (256 nodes per bucket)
#define BCAP 9216             // slots per bucket region (mean ~8184, sd ~90)
#define MAXB 512              // LDS table size; requires nbuckets <= 512
#define OVF_CAP 8192

__global__ void seed_k(int* __restrict__ gcur, int nbuckets, int* __restrict__ ovf_cnt) {
    int i = blockIdx.x * blockDim.x + threadIdx.x;
    if (i < nbuckets) gcur[i] = i * BCAP;
    if (i == 0) *ovf_cnt = 0;
}

// Pass A: two sweeps over this block's 8192-edge range.
// sweep1: LDS bucket histogram. between: one global atomicAdd per nonzero bucket.
// sweep2: re-read edges, rank via LDS atomics, write packed value into bucket region.
__global__ __launch_bounds__(256) void binA(
        const int* __restrict__ src, const int* __restrict__ dst,
        int* __restrict__ gcur, int* __restrict__ padded,
        int2* __restrict__ ovf, int* __restrict__ ovf_cnt, int E) {
    __shared__ int hist[MAXB], gb[MAXB];
    int tid = threadIdx.x;
    int e0 = blockIdx.x * 8192;
    int e1 = min(e0 + 8192, E);
    for (int b = tid; b < MAXB; b += 256) hist[b] = 0;
    __syncthreads();
    for (int e = e0 + tid; e < e1; e += 256)
        atomicAdd(&hist[dst[e] >> BSH], 1);
    __syncthreads();
    for (int b = tid; b < MAXB; b += 256) {
        int h = hist[b];
        gb[b] = h ? atomicAdd(&gcur[b], h) : 0;
        hist[b] = 0;
    }
    __syncthreads();
    for (int e = e0 + tid; e < e1; e += 256) {
        int s = src[e], d = dst[e];
        int b = d >> BSH;
        int r = atomicAdd(&hist[b], 1);
        int pos = gb[b] + r;
        if (pos < (b + 1) * BCAP) {
            padded[pos] = (s << BSH) | (d & ((1 << BSH) - 1));
        } else {
            int k = atomicAdd(ovf_cnt, 1);
            if (k < OVF_CAP) ovf[k] = make_int2(s, d);
        }
    }
}

// Pass B: one block per bucket. LDS counting sort by dst_low8.
// Emits og[node]=(off,cnt), deg[node], and writes sorted src list back in place.
__global__ __launch_bounds__(256) void binB(
        const int* __restrict__ gcur, int* __restrict__ padded,
        int2* __restrict__ og, int* __restrict__ deg, int n) {
    __shared__ int bins[256], scanb[256], sA[256];
    __shared__ int sorted[BCAP];
    int k = blockIdx.x, tid = threadIdx.x;
    int base = k * BCAP;
    int cnt = gcur[k] - base;
    if (cnt > BCAP) cnt = BCAP;
    if (cnt < 0) cnt = 0;
    bins[tid] = 0;
    __syncthreads();
    for (int i = tid; i < cnt; i += 256)
        atomicAdd(&bins[padded[base + i] & 255], 1);
    __syncthreads();
    sA[tid] = bins[tid];
    __syncthreads();
    for (int d = 1; d < 256; d <<= 1) {
        int v = sA[tid];
        int a = (tid >= d) ? sA[tid - d] : 0;
        __syncthreads();
        sA[tid] = v + a;
        __syncthreads();
    }
    int excl = sA[tid] - bins[tid];
    scanb[tid] = excl;
    int node = (k << BSH) + tid;
    if (node < n) {
        og[node] = make_int2(base + excl, bins[tid]);
        deg[node] = bins[tid];
    }
    bins[tid] = 0;
    __syncthreads();
    for (int i = tid; i < cnt; i += 256) {
        int v = padded[base + i];
        int lo = v & 255;
        int r = atomicAdd(&bins[lo], 1);
        sorted[scanb[lo] + r] = v >> BSH;
    }
    __syncthreads();
    for (int i = tid; i < cnt; i += 256) padded[base + i] = sorted[i];
}

// overflow edges count toward true degree
__global__ void fixdeg_k(const int2* __restrict__ ovf, const int* __restrict__ ovf_cnt,
                         int* __restrict__ deg) {
    int c = *ovf_cnt;
    if (c > OVF_CAP) c = OVF_CAP;
    for (int i = blockIdx.x * blockDim.x + threadIdx.x; i < c;
         i += gridDim.x * blockDim.x)
        atomicAdd(&deg[ovf[i].y], 1);
}

__global__ void dinv_k(const int* __restrict__ deg, float* __restrict__ dinv, int n) {
    int i = blockIdx.x * blockDim.x + threadIdx.x;
    if (i < n) dinv[i] = rsqrtf((float)deg[i] + 1.0f);  // +1 = self-loop
}

// t1d[i][h] = (sum_k x[i][k] * W1[k][h]) * dinv[i]
__global__ __launch_bounds__(256) void gemm1_k(
        const float* __restrict__ x, const float* __restrict__ W1,
        const float* __restrict__ dinv, float* __restrict__ t1d, int n) {
    __shared__ float W1s[256 * 16];
    for (int i = threadIdx.x; i < 256 * 16; i += 256) W1s[i] = W1[i];
    __syncthreads();
    int node = blockIdx.x * 16 + (threadIdx.x >> 4);
    int hid  = threadIdx.x & 15;
    if (node >= n) return;
    const float4* x4 = (const float4*)(x + (size_t)node * 256);
    float acc = 0.f;
#pragma unroll 8
    for (int k4 = 0; k4 < 64; ++k4) {
        float4 xv = x4[k4];
        int kb = k4 * 64 + hid;
        acc += xv.x * W1s[kb] + xv.y * W1s[kb + 16]
             + xv.z * W1s[kb + 32] + xv.w * W1s[kb + 48];
    }
    t1d[(size_t)node * 16 + hid] = acc * dinv[node];
}

// S[d] = feat[d] + sum_{CSR} feat[src]   (unscaled; bias/relu applied later)
__global__ __launch_bounds__(256) void agg_k(
        const int2* __restrict__ og, const int* __restrict__ padded,
        const float* __restrict__ feat, float* __restrict__ S, int n) {
    int node = blockIdx.x * 64 + (threadIdx.x >> 2);
    int q    = threadIdx.x & 3;
    if (node >= n) return;
    const float4* f4 = (const float4*)feat;
    float4 acc = f4[(size_t)node * 4 + q];  // self-loop term
    int2 o = og[node];
    int b = o.x, c = o.y, j = 0;
    for (; j + 4 <= c; j += 4) {
        int s0 = padded[b + j],     s1 = padded[b + j + 1];
        int s2 = padded[b + j + 2], s3 = padded[b + j + 3];
        float4 v0 = f4[(size_t)s0 * 4 + q];
        float4 v1 = f4[(size_t)s1 * 4 + q];
        float4 v2 = f4[(size_t)s2 * 4 + q];
        float4 v3 = f4[(size_t)s3 * 4 + q];
        acc.x += (v0.x + v1.x) + (v2.x + v3.x);
        acc.y += (v0.y + v1.y) + (v2.y + v3.y);
        acc.z += (v0.z + v1.z) + (v2.z + v3.z);
        acc.w += (v0.w + v1.w) + (v2.w + v3.w);
    }
    for (; j < c; ++j) {
        float4 v = f4[(size_t)padded[b + j] * 4 + q];
        acc.x += v.x; acc.y += v.y; acc.z += v.z; acc.w += v.w;
    }
    ((float4*)S)[(size_t)node * 4 + q] = acc;
}

// overflow edges: S[dst] += feat[src]
__global__ void fixS_k(const int2* __restrict__ ovf, const int* __restrict__ ovf_cnt,
                       const float* __restrict__ feat, float* __restrict__ S) {
    int c = *ovf_cnt;
    if (c > OVF_CAP) c = OVF_CAP;
    for (int i = blockIdx.x * blockDim.x + threadIdx.x; i < c;
         i += gridDim.x * blockDim.x) {
        int2 e = ovf[i];
        for (int h = 0; h < 16; ++h)
            atomicAdd(&S[(size_t)e.y * 16 + h], feat[(size_t)e.x * 16 + h]);
    }
}

// hd[i] = relu(b1 + dinv[i]*S[i]) * dinv[i]   (in place)
__global__ void relu_k(float* __restrict__ S, const float* __restrict__ dinv,
                       const float* __restrict__ b1, int n) {
    int node = blockIdx.x * blockDim.x + threadIdx.x;
    if (node >= n) return;
    float di = dinv[node];
    float4* row = (float4*)S + (size_t)node * 4;
    const float4* b4 = (const float4*)b1;
#pragma unroll
    for (int q = 0; q < 4; ++q) {
        float4 v = row[q], b = b4[q];
        v.x = fmaxf(b.x + di * v.x, 0.f) * di;
        v.y = fmaxf(b.y + di * v.y, 0.f) * di;
        v.z = fmaxf(b.z + di * v.z, 0.f) * di;
        v.w = fmaxf(b.w + di * v.w, 0.f) * di;
        row[q] = v;
    }
}

// logits = b2 + (dinv*S2) @ W2; out = logits - logsumexp
__global__ __launch_bounds__(256) void final_k(
        const float* __restrict__ S2, const float* __restrict__ dinv,
        const float* __restrict__ W2, const float* __restrict__ b2,
        float* __restrict__ out, int n) {
    __shared__ float W2s[16 * 40];
    __shared__ float b2s[40];
    for (int i = threadIdx.x; i < 640; i += 256) W2s[i] = W2[i];
    if (threadIdx.x < 40) b2s[threadIdx.x] = b2[threadIdx.x];
    __syncthreads();
    int node = blockIdx.x * blockDim.x + threadIdx.x;
    if (node >= n) return;
    float di = dinv[node];
    float g[16];
    const float4* a4 = (const float4*)(S2 + (size_t)node * 16);
    float4 t0 = a4[0], t1 = a4[1], t2 = a4[2], t3 = a4[3];
    g[0]=di*t0.x; g[1]=di*t0.y; g[2]=di*t0.z; g[3]=di*t0.w;
    g[4]=di*t1.x; g[5]=di*t1.y; g[6]=di*t1.z; g[7]=di*t1.w;
    g[8]=di*t2.x; g[9]=di*t2.y; g[10]=di*t2.z; g[11]=di*t2.w;
    g[12]=di*t3.x; g[13]=di*t3.y; g[14]=di*t3.z; g[15]=di*t3.w;
    float lg[40];
    float mx = -1e30f;
#pragma unroll
    for (int j = 0; j < 40; ++j) {
        float acc = b2s[j];
#pragma unroll
        for (int k = 0; k < 16; ++k) acc += g[k] * W2s[k * 40 + j];
        lg[j] = acc;
        mx = fmaxf(mx, acc);
    }
    float sum = 0.f;
#pragma unroll
    for (int j = 0; j < 40; ++j) sum += __expf(lg[j] - mx);
    float lse = mx + logf(sum);
    float4* o4 = (float4*)(out + (size_t)node * 40);
#pragma unroll
    for (int j = 0; j < 10; ++j) {
        float4 v;
        v.x = lg[4 * j + 0] - lse;
        v.y = lg[4 * j + 1] - lse;
        v.z = lg[4 * j + 2] - lse;
        v.w = lg[4 * j + 3] - lse;
        o4[j] = v;
    }
}

extern "C" void kernel_launch(void* const* d_in, const int* in_sizes, int n_in,
                              void* d_out, int out_size, void* d_ws, size_t ws_size,
                              hipStream_t stream) {
    const float* x  = (const float*)d_in[0];
    const int*   ei = (const int*)d_in[1];
    const float* W1 = (const float*)d_in[2];
    const float* b1 = (const float*)d_in[3];
    const float* W2 = (const float*)d_in[4];
    const float* b2 = (const float*)d_in[5];

    int n = in_sizes[0] / 256;
    int E = in_sizes[1] / 2;
    const int* srcp = ei;       // edge_index[0]
    const int* dstp = ei + E;   // edge_index[1]

    int nbuckets = (n + 255) >> BSH;   // <= MAXB

    // ws layout (4-byte words, 8B-aligned where needed):
    // og 2n | deg n | dinv n | gcur MAXB | ovf_cnt 16 | ovf 2*OVF_CAP
    // | bufA 16n | bufB 16n | padded nbuckets*BCAP
    int2*  og      = (int2*)d_ws;                       // 2n words
    int*   deg     = (int*)d_ws + 2 * (size_t)n;        // n
    float* dinv    = (float*)((int*)d_ws + 3 * (size_t)n);  // n
    int*   gcur    = (int*)d_ws + 4 * (size_t)n;        // MAXB
    int*   ovf_cnt = gcur + MAXB;                       // 16
    int2*  ovf     = (int2*)(ovf_cnt + 16);             // 2*OVF_CAP words
    float* bufA    = (float*)(ovf_cnt + 16 + 2 * OVF_CAP);  // 16n : t1d, later S2
    float* bufB    = bufA + 16 * (size_t)n;                 // 16n : S1 -> hd
    int*   padded  = (int*)(bufB + 16 * (size_t)n);     // nbuckets*BCAP
    float* out     = (float*)d_out;

    int gb_n = (n + 255) / 256;

    seed_k  <<<(nbuckets + 255) / 256, 256, 0, stream>>>(gcur, nbuckets, ovf_cnt);
    binA    <<<(E + 8191) / 8192, 256, 0, stream>>>(srcp, dstp, gcur, padded, ovf, ovf_cnt, E);
    binB    <<<nbuckets, 256, 0, stream>>>(gcur, padded, og, deg, n);
    fixdeg_k<<<16, 256, 0, stream>>>(ovf, ovf_cnt, deg);
    dinv_k  <<<gb_n, 256, 0, stream>>>(deg, dinv, n);
    gemm1_k <<<(n + 15) / 16, 256, 0, stream>>>(x, W1, dinv, bufA, n);
    agg_k   <<<(n + 63) / 64, 256, 0, stream>>>(og, padded, bufA, bufB, n);  // layer 1 sums
    fixS_k  <<<16, 256, 0, stream>>>(ovf, ovf_cnt, bufA, bufB);
    relu_k  <<<gb_n, 256, 0, stream>>>(bufB, dinv, b1, n);                   // bufB = hd
    agg_k   <<<(n + 63) / 64, 256, 0, stream>>>(og, padded, bufB, bufA, n);  // layer 2 sums
    fixS_k  <<<16, 256, 0, stream>>>(ovf, ovf_cnt, bufB, bufA);
    final_k <<<gb_n, 256, 0, stream>>>(bufA, dinv, W2, b2, out, n);
}

// Round 7
// 382.592 us; speedup vs baseline: 14.6894x; 1.1051x over previous
//
#include <hip/hip_runtime.h>
#include <hip/hip_bf16.h>

// 2-layer GCN, HID=16 space for both aggregations (Ahat·(h@W2) == (Ahat·h)@W2),
// edge weight dinv[s]*dinv[d] factored into per-node feature pre-scaling.
// Adjacency via two-level LDS counting sort (R5: ~153k global RMW vs 3.2M).
// R6: gemm1 (x@W1, M=100k K=256 N=16) moved to MFMA bf16: R5's vector version
// issued 16x redundant global loads (each hid-thread read the whole row) and was
// load-issue bound at 92us. bf16+f32-acc error ~0.004 << 0.079 threshold.

#define BSH 8                 // bucket = dst >> 8  (256 nodes per bucket)
#define BCAP 9216             // slots per bucket region (mean ~8184, sd ~90)
#define MAXB 512              // LDS table size; requires nbuckets <= 512
#define OVF_CAP 8192

typedef __attribute__((ext_vector_type(8))) short bf16x8;
typedef __attribute__((ext_vector_type(4))) float f32x4;

__device__ __forceinline__ short f2b(float f) {
    __hip_bfloat16 h = __float2bfloat16(f);   // RNE
    return *reinterpret_cast<short*>(&h);
}

__global__ void seed_k(int* __restrict__ gcur, int nbuckets, int* __restrict__ ovf_cnt) {
    int i = blockIdx.x * blockDim.x + threadIdx.x;
    if (i < nbuckets) gcur[i] = i * BCAP;
    if (i == 0) *ovf_cnt = 0;
}

// Pass A: LDS bucket histogram -> one global atomicAdd per (block,bucket) ->
// scatter packed (src<<8|dst_low) into padded bucket regions.
__global__ __launch_bounds__(256) void binA(
        const int* __restrict__ src, const int* __restrict__ dst,
        int* __restrict__ gcur, int* __restrict__ padded,
        int2* __restrict__ ovf, int* __restrict__ ovf_cnt, int E) {
    __shared__ int hist[MAXB], gb[MAXB];
    int tid = threadIdx.x;
    int e0 = blockIdx.x * 8192;
    int e1 = min(e0 + 8192, E);
    for (int b = tid; b < MAXB; b += 256) hist[b] = 0;
    __syncthreads();
    for (int e = e0 + tid; e < e1; e += 256)
        atomicAdd(&hist[dst[e] >> BSH], 1);
    __syncthreads();
    for (int b = tid; b < MAXB; b += 256) {
        int h = hist[b];
        gb[b] = h ? atomicAdd(&gcur[b], h) : 0;
        hist[b] = 0;
    }
    __syncthreads();
    for (int e = e0 + tid; e < e1; e += 256) {
        int s = src[e], d = dst[e];
        int b = d >> BSH;
        int r = atomicAdd(&hist[b], 1);
        int pos = gb[b] + r;
        if (pos < (b + 1) * BCAP) {
            padded[pos] = (s << BSH) | (d & ((1 << BSH) - 1));
        } else {
            int k = atomicAdd(ovf_cnt, 1);
            if (k < OVF_CAP) ovf[k] = make_int2(s, d);
        }
    }
}

// Pass B: per-bucket LDS counting sort by dst_low8 -> sorted CSR + degrees.
__global__ __launch_bounds__(256) void binB(
        const int* __restrict__ gcur, int* __restrict__ padded,
        int2* __restrict__ og, int* __restrict__ deg, int n) {
    __shared__ int bins[256], scanb[256], sA[256];
    __shared__ int sorted[BCAP];
    int k = blockIdx.x, tid = threadIdx.x;
    int base = k * BCAP;
    int cnt = gcur[k] - base;
    if (cnt > BCAP) cnt = BCAP;
    if (cnt < 0) cnt = 0;
    bins[tid] = 0;
    __syncthreads();
    for (int i = tid; i < cnt; i += 256)
        atomicAdd(&bins[padded[base + i] & 255], 1);
    __syncthreads();
    sA[tid] = bins[tid];
    __syncthreads();
    for (int d = 1; d < 256; d <<= 1) {
        int v = sA[tid];
        int a = (tid >= d) ? sA[tid - d] : 0;
        __syncthreads();
        sA[tid] = v + a;
        __syncthreads();
    }
    int excl = sA[tid] - bins[tid];
    scanb[tid] = excl;
    int node = (k << BSH) + tid;
    if (node < n) {
        og[node] = make_int2(base + excl, bins[tid]);
        deg[node] = bins[tid];
    }
    bins[tid] = 0;
    __syncthreads();
    for (int i = tid; i < cnt; i += 256) {
        int v = padded[base + i];
        int lo = v & 255;
        int r = atomicAdd(&bins[lo], 1);
        sorted[scanb[lo] + r] = v >> BSH;
    }
    __syncthreads();
    for (int i = tid; i < cnt; i += 256) padded[base + i] = sorted[i];
}

__global__ void fixdeg_k(const int2* __restrict__ ovf, const int* __restrict__ ovf_cnt,
                         int* __restrict__ deg) {
    int c = *ovf_cnt;
    if (c > OVF_CAP) c = OVF_CAP;
    for (int i = blockIdx.x * blockDim.x + threadIdx.x; i < c;
         i += gridDim.x * blockDim.x)
        atomicAdd(&deg[ovf[i].y], 1);
}

__global__ void dinv_k(const int* __restrict__ deg, float* __restrict__ dinv, int n) {
    int i = blockIdx.x * blockDim.x + threadIdx.x;
    if (i < n) dinv[i] = rsqrtf((float)deg[i] + 1.0f);  // +1 = self-loop
}

// t1d = (x @ W1) * dinv, via MFMA bf16. Block = 256 thr = 4 waves = 64 nodes.
// A-frag: A[m=lane&15][k=quad*8+j]; B-frag: B[n=lane&15][k=quad*8+j];
// C/D:   col(n)=lane&15, row(m)=quad*4+reg   [verified layouts per guide m89/m91]
__global__ __launch_bounds__(256) void gemm1_mfma(
        const float* __restrict__ x, const float* __restrict__ W1,
        const float* __restrict__ dinv, float* __restrict__ t1d, int n) {
    __shared__ __align__(16) short xs[64 * 264];  // 64 rows, stride 264 bf16 (16B-aligned, bank-safe)
    __shared__ short w1s[256 * 16];
    int tid = threadIdx.x;
    int base = blockIdx.x * 64;
    int rows = n - base; if (rows > 64) rows = 64;

    for (int i = tid; i < 4096; i += 256) w1s[i] = f2b(W1[i]);
    for (int i = tid; i < 4096; i += 256) {        // 4096 float4 = 64 rows x 64
        int r = i >> 6, c = i & 63;
        if (r < rows) {
            float4 v = ((const float4*)(x + (size_t)(base + r) * 256))[c];
            short4 b;
            b.x = f2b(v.x); b.y = f2b(v.y); b.z = f2b(v.z); b.w = f2b(v.w);
            *(short4*)&xs[r * 264 + c * 4] = b;
        }
    }
    __syncthreads();

    int lane = tid & 63, wave = tid >> 6;
    int q = lane >> 4, m = lane & 15;

    bf16x8 bfrag[8];
#pragma unroll
    for (int t = 0; t < 8; ++t)
#pragma unroll
        for (int j = 0; j < 8; ++j)
            bfrag[t][j] = w1s[(t * 32 + q * 8 + j) * 16 + m];

    f32x4 acc = {0.f, 0.f, 0.f, 0.f};
    int arow = wave * 16 + m;
#pragma unroll
    for (int t = 0; t < 8; ++t) {
        bf16x8 a = *(const bf16x8*)&xs[arow * 264 + t * 32 + q * 8];
        acc = __builtin_amdgcn_mfma_f32_16x16x32_bf16(a, bfrag[t], acc, 0, 0, 0);
    }
#pragma unroll
    for (int r = 0; r < 4; ++r) {
        int node = base + wave * 16 + q * 4 + r;
        if (node < n)
            t1d[(size_t)node * 16 + m] = acc[r] * dinv[node];
    }
}

// S[d] = feat[d] + sum_{CSR} feat[src]   (unscaled; bias/relu applied later)
__global__ __launch_bounds__(256) void agg_k(
        const int2* __restrict__ og, const int* __restrict__ padded,
        const float* __restrict__ feat, float* __restrict__ S, int n) {
    int node = blockIdx.x * 64 + (threadIdx.x >> 2);
    int q    = threadIdx.x & 3;
    if (node >= n) return;
    const float4* f4 = (const float4*)feat;
    float4 acc = f4[(size_t)node * 4 + q];  // self-loop term
    int2 o = og[node];
    int b = o.x, c = o.y, j = 0;
    for (; j + 4 <= c; j += 4) {
        int s0 = padded[b + j],     s1 = padded[b + j + 1];
        int s2 = padded[b + j + 2], s3 = padded[b + j + 3];
        float4 v0 = f4[(size_t)s0 * 4 + q];
        float4 v1 = f4[(size_t)s1 * 4 + q];
        float4 v2 = f4[(size_t)s2 * 4 + q];
        float4 v3 = f4[(size_t)s3 * 4 + q];
        acc.x += (v0.x + v1.x) + (v2.x + v3.x);
        acc.y += (v0.y + v1.y) + (v2.y + v3.y);
        acc.z += (v0.z + v1.z) + (v2.z + v3.z);
        acc.w += (v0.w + v1.w) + (v2.w + v3.w);
    }
    for (; j < c; ++j) {
        float4 v = f4[(size_t)padded[b + j] * 4 + q];
        acc.x += v.x; acc.y += v.y; acc.z += v.z; acc.w += v.w;
    }
    ((float4*)S)[(size_t)node * 4 + q] = acc;
}

__global__ void fixS_k(const int2* __restrict__ ovf, const int* __restrict__ ovf_cnt,
                       const float* __restrict__ feat, float* __restrict__ S) {
    int c = *ovf_cnt;
    if (c > OVF_CAP) c = OVF_CAP;
    for (int i = blockIdx.x * blockDim.x + threadIdx.x; i < c;
         i += gridDim.x * blockDim.x) {
        int2 e = ovf[i];
        for (int h = 0; h < 16; ++h)
            atomicAdd(&S[(size_t)e.y * 16 + h], feat[(size_t)e.x * 16 + h]);
    }
}

// hd[i] = relu(b1 + dinv[i]*S[i]) * dinv[i]   (in place)
__global__ void relu_k(float* __restrict__ S, const float* __restrict__ dinv,
                       const float* __restrict__ b1, int n) {
    int node = blockIdx.x * blockDim.x + threadIdx.x;
    if (node >= n) return;
    float di = dinv[node];
    float4* row = (float4*)S + (size_t)node * 4;
    const float4* b4 = (const float4*)b1;
#pragma unroll
    for (int q = 0; q < 4; ++q) {
        float4 v = row[q], b = b4[q];
        v.x = fmaxf(b.x + di * v.x, 0.f) * di;
        v.y = fmaxf(b.y + di * v.y, 0.f) * di;
        v.z = fmaxf(b.z + di * v.z, 0.f) * di;
        v.w = fmaxf(b.w + di * v.w, 0.f) * di;
        row[q] = v;
    }
}

// logits = b2 + (dinv*S2) @ W2; out = logits - logsumexp
__global__ __launch_bounds__(256) void final_k(
        const float* __restrict__ S2, const float* __restrict__ dinv,
        const float* __restrict__ W2, const float* __restrict__ b2,
        float* __restrict__ out, int n) {
    __shared__ float W2s[16 * 40];
    __shared__ float b2s[40];
    for (int i = threadIdx.x; i < 640; i += 256) W2s[i] = W2[i];
    if (threadIdx.x < 40) b2s[threadIdx.x] = b2[threadIdx.x];
    __syncthreads();
    int node = blockIdx.x * blockDim.x + threadIdx.x;
    if (node >= n) return;
    float di = dinv[node];
    float g[16];
    const float4* a4 = (const float4*)(S2 + (size_t)node * 16);
    float4 t0 = a4[0], t1 = a4[1], t2 = a4[2], t3 = a4[3];
    g[0]=di*t0.x; g[1]=di*t0.y; g[2]=di*t0.z; g[3]=di*t0.w;
    g[4]=di*t1.x; g[5]=di*t1.y; g[6]=di*t1.z; g[7]=di*t1.w;
    g[8]=di*t2.x; g[9]=di*t2.y; g[10]=di*t2.z; g[11]=di*t2.w;
    g[12]=di*t3.x; g[13]=di*t3.y; g[14]=di*t3.z; g[15]=di*t3.w;
    float lg[40];
    float mx = -1e30f;
#pragma unroll
    for (int j = 0; j < 40; ++j) {
        float acc = b2s[j];
#pragma unroll
        for (int k = 0; k < 16; ++k) acc += g[k] * W2s[k * 40 + j];
        lg[j] = acc;
        mx = fmaxf(mx, acc);
    }
    float sum = 0.f;
#pragma unroll
    for (int j = 0; j < 40; ++j) sum += __expf(lg[j] - mx);
    float lse = mx + logf(sum);
    float4* o4 = (float4*)(out + (size_t)node * 40);
#pragma unroll
    for (int j = 0; j < 10; ++j) {
        float4 v;
        v.x = lg[4 * j + 0] - lse;
        v.y = lg[4 * j + 1] - lse;
        v.z = lg[4 * j + 2] - lse;
        v.w = lg[4 * j + 3] - lse;
        o4[j] = v;
    }
}

extern "C" void kernel_launch(void* const* d_in, const int* in_sizes, int n_in,
                              void* d_out, int out_size, void* d_ws, size_t ws_size,
                              hipStream_t stream) {
    const float* x  = (const float*)d_in[0];
    const int*   ei = (const int*)d_in[1];
    const float* W1 = (const float*)d_in[2];
    const float* b1 = (const float*)d_in[3];
    const float* W2 = (const float*)d_in[4];
    const float* b2 = (const float*)d_in[5];

    int n = in_sizes[0] / 256;
    int E = in_sizes[1] / 2;
    const int* srcp = ei;       // edge_index[0]
    const int* dstp = ei + E;   // edge_index[1]

    int nbuckets = (n + 255) >> BSH;   // <= MAXB

    int2*  og      = (int2*)d_ws;                       // 2n words
    int*   deg     = (int*)d_ws + 2 * (size_t)n;        // n
    float* dinv    = (float*)((int*)d_ws + 3 * (size_t)n);  // n
    int*   gcur    = (int*)d_ws + 4 * (size_t)n;        // MAXB
    int*   ovf_cnt = gcur + MAXB;                       // 16
    int2*  ovf     = (int2*)(ovf_cnt + 16);             // 2*OVF_CAP words
    float* bufA    = (float*)(ovf_cnt + 16 + 2 * OVF_CAP);  // 16n : t1d, later S2
    float* bufB    = bufA + 16 * (size_t)n;                 // 16n : S1 -> hd
    int*   padded  = (int*)(bufB + 16 * (size_t)n);     // nbuckets*BCAP
    float* out     = (float*)d_out;

    int gb_n = (n + 255) / 256;

    seed_k    <<<(nbuckets + 255) / 256, 256, 0, stream>>>(gcur, nbuckets, ovf_cnt);
    binA      <<<(E + 8191) / 8192, 256, 0, stream>>>(srcp, dstp, gcur, padded, ovf, ovf_cnt, E);
    binB      <<<nbuckets, 256, 0, stream>>>(gcur, padded, og, deg, n);
    fixdeg_k  <<<16, 256, 0, stream>>>(ovf, ovf_cnt, deg);
    dinv_k    <<<gb_n, 256, 0, stream>>>(deg, dinv, n);
    gemm1_mfma<<<(n + 63) / 64, 256, 0, stream>>>(x, W1, dinv, bufA, n);
    agg_k     <<<(n + 63) / 64, 256, 0, stream>>>(og, padded, bufA, bufB, n);  // layer 1 sums
    fixS_k    <<<16, 256, 0, stream>>>(ovf, ovf_cnt, bufA, bufB);
    relu_k    <<<gb_n, 256, 0, stream>>>(bufB, dinv, b1, n);                   // bufB = hd
    agg_k     <<<(n + 63) / 64, 256, 0, stream>>>(og, padded, bufB, bufA, n);  // layer 2 sums
    fixS_k    <<<16, 256, 0, stream>>>(ovf, ovf_cnt, bufB, bufA);
    final_k   <<<gb_n, 256, 0, stream>>>(bufA, dinv, W2, b2, out, n);
}